// Round 2
// baseline (560.624 us; speedup 1.0000x reference)
//
#include <hip/hip_runtime.h>

// DecisionGate:
//   g          = 1 / (1 + |x|^4)                      [4096, 64]  (A=1, 2B=4)
//   mask       = g >= 0.5                             [4096, 64]  (written as 0/1 float)
//   dispatched = (mask ? g : 0)[b,p] * act[b,d]       [4096, 64, 512]
//
// Output layout (flat float32): g [0..256K), mask [256K..512K), disp [512K..)
//
// Roofline: ~540 MB writes + ~70 MB reads -> ~95 us kernel at 6.3 TB/s.
// Timed region also contains the harness's ~343 us poison fill -> dur floor ~440.
//
// v3 theory: v1 (4096 big blocks) and v2 (32768 small blocks) both hit the
// same ~2.9 TB/s despite opposite residency shapes -> window theory dead.
// Remaining difference vs the 6.3 TB/s fill: the fill is PERSISTENT waves in
// a grid-stride loop issuing one monotonic ascending store sweep; mine were
// short-lived waves with per-block sweeps. v3 reproduces the fill's structure
// exactly: 2048 persistent blocks, grid-stride over the disp float4 space in
// pure ascending order (8 MB contiguous window per iteration), stores issued
// back-to-back from long-lived waves. Per-thread p/d4 are loop-invariant
// (stride 2^19 f4 == 0 mod 8192), so the inner loop is load/gate/mul/store.

constexpr int BATCH = 4096;
constexpr int P = 64;
constexpr int D = 512;

constexpr int NTHR = 256;
constexpr int NBLK = 2048;                       // 8 wg/CU on 256 CUs: all resident
constexpr int GSTRIDE = NBLK * NTHR;             // 524288 float4s = 8 MB per sweep step
constexpr long long NF4 = (long long)BATCH * P * (D / 4);   // 33554432
constexpr int NITER = (int)(NF4 / GSTRIDE);      // 64, exact (no tail)

typedef float vfloat4 __attribute__((ext_vector_type(4)));

__device__ __forceinline__ float gate_val(float xv) {
    const float x2 = xv * xv;
    const float x4 = x2 * x2;          // |x/A|^(2B) with A=1, B=2
    return 1.0f / (1.0f + x4);
}

__global__ __launch_bounds__(NTHR)
void decision_gate_kernel(const float* __restrict__ x,
                          const float* __restrict__ act,
                          float* __restrict__ g_out,
                          float* __restrict__ mask_out,
                          float* __restrict__ disp) {
    const int gid = blockIdx.x * NTHR + threadIdx.x;

    // --- g / mask: first 65536 threads each own one float4 of x ---
    if (gid < (BATCH * P) / 4) {
        const vfloat4 xv = reinterpret_cast<const vfloat4*>(x)[gid];
        vfloat4 gv, mv;
        #pragma unroll
        for (int i = 0; i < 4; ++i) {
            const float g = gate_val(xv[i]);
            gv[i] = g;
            mv[i] = (g >= 0.5f) ? 1.0f : 0.0f;
        }
        reinterpret_cast<vfloat4*>(g_out)[gid]    = gv;
        reinterpret_cast<vfloat4*>(mask_out)[gid] = mv;
    }

    // --- dispatch: persistent grid-stride ascending sweep ---
    // f = gid + it*GSTRIDE ; b = f>>13 ; p = (f>>7)&63 ; d4 = f&127.
    // GSTRIDE % 8192 == 0  =>  p, d4 loop-invariant; b = b0 + 64*it.
    const int b0 = gid >> 13;
    const int p  = (gid >> 7) & (P - 1);
    const int d4 = gid & (D / 4 - 1);

    const vfloat4* __restrict__ actv = reinterpret_cast<const vfloat4*>(act);
    vfloat4* __restrict__ dispv      = reinterpret_cast<vfloat4*>(disp);

    #pragma unroll 4
    for (int it = 0; it < NITER; ++it) {
        const int b = b0 + 64 * it;
        const float xv = x[b * P + p];                 // wave-uniform, L1/L2-hot
        const float g  = gate_val(xv);
        const float wp = (g >= 0.5f) ? g : 0.0f;
        const vfloat4 v = actv[b * (D / 4) + d4] * wp; // 1 KB/wave contiguous, L2-hot
        __builtin_nontemporal_store(v, &dispv[(size_t)gid + (size_t)it * GSTRIDE]);
    }
}

extern "C" void kernel_launch(void* const* d_in, const int* in_sizes, int n_in,
                              void* d_out, int out_size, void* d_ws, size_t ws_size,
                              hipStream_t stream) {
    const float* x   = (const float*)d_in[0];   // [4096, 64]
    const float* act = (const float*)d_in[1];   // [4096, 512]
    // d_in[2] = batch_inds (int64) -- not needed for the dense outputs.

    float* out      = (float*)d_out;
    float* g_out    = out;                       // 4096*64
    float* mask_out = out + (size_t)BATCH * P;   // 4096*64
    float* disp     = out + (size_t)2 * BATCH * P;

    decision_gate_kernel<<<NBLK, NTHR, 0, stream>>>(x, act, g_out, mask_out, disp);
}

// Round 4
// 521.362 us; speedup vs baseline: 1.0753x; 1.0753x over previous
//
#include <hip/hip_runtime.h>

// DecisionGate:
//   g          = 1 / (1 + |x|^4)                      [4096, 64]  (A=1, 2B=4)
//   mask       = g >= 0.5                             [4096, 64]  (written as 0/1 float)
//   dispatched = (mask ? g : 0)[b,p] * act[b,d]       [4096, 64, 512]
//
// Output layout (flat float32): g [0..256K), mask [256K..512K), disp [512K..)
//
// Roofline: ~540 MB writes + 9 MB reads -> ~87 us kernel at the fill's 6.3 TB/s.
// Timed region also contains the harness's ~343 us poison fill -> dur floor ~430.
//
// v4 (RESUBMIT -- previous round died on container acquire, not on the kernel):
// v1/v2/v3 varied residency window, block size, persistence, and NT-vs-plain
// stores -- all land at ~2.5-2.9 TB/s. The ONE axis never varied: waves/CU
// (always 32 -> ~1024 concurrent store streams per XCD-L2). The 6.3 TB/s fill
// runs at Occupancy ~10% = ~3.3 waves/CU = ~105 streams per L2, each wave
// streaming MBs. Theory: L2->HBM writeback keeps DRAM row locality only with
// few concurrent store streams per L2; ~1000 streams randomize writeback order
// -> page thrash -> half bandwidth. v4 clones the fill's shape: 256 blocks x
// 256 thr (4 waves/CU, ~128 streams/XCD), per-wave contiguous 32 KB segments,
// plain stores, reads minimized to one pass over act (registers) + x.

constexpr int BATCH = 4096;
constexpr int P = 64;
constexpr int D = 512;

constexpr int NTHR = 256;               // 4 waves per block
constexpr int NBLK = 256;               // 1 block/CU -> 4 waves/CU, like the fill
constexpr int ROWS = BATCH / NBLK;      // 16 rows per block

typedef float vfloat4 __attribute__((ext_vector_type(4)));

__device__ __forceinline__ float gate_val(float xv) {
    const float x2 = xv * xv;
    const float x4 = x2 * x2;           // |x/A|^(2B) with A=1, B=2
    return 1.0f / (1.0f + x4);
}

__global__ __launch_bounds__(NTHR, 1)
void decision_gate_kernel(const float* __restrict__ x,
                          const float* __restrict__ act,
                          float* __restrict__ g_out,
                          float* __restrict__ mask_out,
                          float* __restrict__ disp) {
    __shared__ float wbuf[2][P];        // double-buffered -> one barrier per row

    const int t    = threadIdx.x;
    const int wave = t >> 6;            // 0..3
    const int lane = t & 63;

    const vfloat4* __restrict__ actv = reinterpret_cast<const vfloat4*>(act);
    vfloat4* __restrict__ dispv      = reinterpret_cast<vfloat4*>(disp);

    for (int k = 0; k < ROWS; ++k) {
        // All 256 blocks work row-band [256k, 256k+256): 32 MB sliding window.
        const int b = blockIdx.x + NBLK * k;

        // Prefetch act row into registers (independent of the barrier below;
        // issued early so HBM latency hides under the gate computation).
        const vfloat4 a0 = actv[(size_t)b * (D / 4) + lane];
        const vfloat4 a1 = actv[(size_t)b * (D / 4) + 64 + lane];

        // Gate for this row: threads 0..63. g/mask written here exactly once.
        if (t < P) {
            const float g = gate_val(x[(size_t)b * P + t]);
            g_out[(size_t)b * P + t]    = g;
            mask_out[(size_t)b * P + t] = (g >= 0.5f) ? 1.0f : 0.0f;
            wbuf[k & 1][t] = (g >= 0.5f) ? g : 0.0f;
        }
        __syncthreads();
        // (No trailing barrier needed: next iter writes the OTHER buffer, and
        //  the iter-k+1 barrier orders those reads before the k+2 overwrite.)

        // Pure plain-store loop. Wave w writes the contiguous 32 KB segment
        // p in [16w, 16w+16) of this row: 32 x 1 KB ascending stores.
        vfloat4* out = dispv + (size_t)b * (P * D / 4);
        #pragma unroll
        for (int i = 0; i < 16; ++i) {
            const int p = 16 * wave + i;
            const float wp = wbuf[k & 1][p];   // wave-uniform -> LDS broadcast
            out[(size_t)p * (D / 4) + lane]      = a0 * wp;
            out[(size_t)p * (D / 4) + 64 + lane] = a1 * wp;
        }
    }
}

extern "C" void kernel_launch(void* const* d_in, const int* in_sizes, int n_in,
                              void* d_out, int out_size, void* d_ws, size_t ws_size,
                              hipStream_t stream) {
    const float* x   = (const float*)d_in[0];   // [4096, 64]
    const float* act = (const float*)d_in[1];   // [4096, 512]
    // d_in[2] = batch_inds (int64) -- not needed for the dense outputs.

    float* out      = (float*)d_out;
    float* g_out    = out;                       // 4096*64
    float* mask_out = out + (size_t)BATCH * P;   // 4096*64
    float* disp     = out + (size_t)2 * BATCH * P;

    decision_gate_kernel<<<NBLK, NTHR, 0, stream>>>(x, act, g_out, mask_out, disp);
}